// Round 1
// baseline (2252.872 us; speedup 1.0000x reference)
//
#include <hip/hip_runtime.h>
#include <hip/hip_bf16.h>

#define N_NODES_C 50000
#define FDIM 64

// h[n][:] = x[n][:]  (the (1+eps)*x self term, eps=0)
__global__ void init_h(const float* __restrict__ x, float* __restrict__ h, int n4) {
    int i = blockIdx.x * blockDim.x + threadIdx.x;
    if (i < n4) {
        ((float4*)h)[i] = ((const float4*)x)[i];
    }
}

// scatter-add: h[dst] += x[src], 16 threads per edge (4 feats each)
__global__ void scatter_edges(const float* __restrict__ x,
                              const int* __restrict__ src,
                              const int* __restrict__ dst,
                              float* __restrict__ h, int n_edges) {
    int t = blockIdx.x * blockDim.x + threadIdx.x;
    int e = t >> 4;
    if (e >= n_edges) return;
    int c = (t & 15) * 4;
    int s = src[e];
    int d = dst[e];
    float4 v = *(const float4*)(x + (size_t)s * FDIM + c);
    float* hp = h + (size_t)d * FDIM + c;
    atomicAdd(hp + 0, v.x);
    atomicAdd(hp + 1, v.y);
    atomicAdd(hp + 2, v.z);
    atomicAdd(hp + 3, v.w);
}

// y = relu( relu(h@W1+b1) @ W2 + b2 )   (outer relu fused; applies to all 3 convs)
__global__ __launch_bounds__(256) void mlp_relu(const float* __restrict__ x,
                                                const float* __restrict__ W1,
                                                const float* __restrict__ b1,
                                                const float* __restrict__ W2,
                                                const float* __restrict__ b2,
                                                float* __restrict__ y, int n_nodes) {
    __shared__ float sW1[FDIM * FDIM];
    __shared__ float sW2[FDIM * FDIM];
    __shared__ float sb1[FDIM];
    __shared__ float sb2[FDIM];
    for (int i = threadIdx.x; i < FDIM * FDIM; i += 256) {
        sW1[i] = W1[i];
        sW2[i] = W2[i];
    }
    if (threadIdx.x < FDIM) {
        sb1[threadIdx.x] = b1[threadIdx.x];
        sb2[threadIdx.x] = b2[threadIdx.x];
    }
    __syncthreads();
    int node = blockIdx.x * 256 + threadIdx.x;
    if (node >= n_nodes) return;

    float h[FDIM];
    const float4* xp = (const float4*)(x + (size_t)node * FDIM);
#pragma unroll
    for (int k = 0; k < FDIM / 4; k++) {
        float4 v = xp[k];
        h[4 * k + 0] = v.x; h[4 * k + 1] = v.y;
        h[4 * k + 2] = v.z; h[4 * k + 3] = v.w;
    }
    float g[FDIM];
    // layer 1: g = relu(h @ W1 + b1); W1 is (64,64) row-major: W1[k][j]=sW1[k*64+j]
    for (int j = 0; j < FDIM; j += 4) {
        float a0 = sb1[j + 0], a1 = sb1[j + 1], a2 = sb1[j + 2], a3 = sb1[j + 3];
#pragma unroll
        for (int k = 0; k < FDIM; k++) {
            float w = h[k];
            a0 += w * sW1[k * FDIM + j + 0];
            a1 += w * sW1[k * FDIM + j + 1];
            a2 += w * sW1[k * FDIM + j + 2];
            a3 += w * sW1[k * FDIM + j + 3];
        }
        g[j + 0] = fmaxf(a0, 0.f); g[j + 1] = fmaxf(a1, 0.f);
        g[j + 2] = fmaxf(a2, 0.f); g[j + 3] = fmaxf(a3, 0.f);
    }
    // layer 2: y = relu(g @ W2 + b2)
    float4* yp = (float4*)(y + (size_t)node * FDIM);
    for (int j = 0; j < FDIM; j += 4) {
        float a0 = sb2[j + 0], a1 = sb2[j + 1], a2 = sb2[j + 2], a3 = sb2[j + 3];
#pragma unroll
        for (int k = 0; k < FDIM; k++) {
            float w = g[k];
            a0 += w * sW2[k * FDIM + j + 0];
            a1 += w * sW2[k * FDIM + j + 1];
            a2 += w * sW2[k * FDIM + j + 2];
            a3 += w * sW2[k * FDIM + j + 3];
        }
        float4 o;
        o.x = fmaxf(a0, 0.f); o.y = fmaxf(a1, 0.f);
        o.z = fmaxf(a2, 0.f); o.w = fmaxf(a3, 0.f);
        yp[j / 4] = o;
    }
}

// out = x @ W_lin + b_lin ; W_lin is (64,10) row-major
__global__ __launch_bounds__(256) void final_linear(const float* __restrict__ x,
                                                    const float* __restrict__ W,
                                                    const float* __restrict__ b,
                                                    float* __restrict__ out, int n_nodes) {
    __shared__ float sW[FDIM * 10];
    __shared__ float sb[10];
    for (int i = threadIdx.x; i < FDIM * 10; i += 256) sW[i] = W[i];
    if (threadIdx.x < 10) sb[threadIdx.x] = b[threadIdx.x];
    __syncthreads();
    int node = blockIdx.x * 256 + threadIdx.x;
    if (node >= n_nodes) return;

    float h[FDIM];
    const float4* xp = (const float4*)(x + (size_t)node * FDIM);
#pragma unroll
    for (int k = 0; k < FDIM / 4; k++) {
        float4 v = xp[k];
        h[4 * k + 0] = v.x; h[4 * k + 1] = v.y;
        h[4 * k + 2] = v.z; h[4 * k + 3] = v.w;
    }
    float acc[10];
#pragma unroll
    for (int c = 0; c < 10; c++) acc[c] = sb[c];
    for (int k = 0; k < FDIM; k++) {
        float w = h[k];
#pragma unroll
        for (int c = 0; c < 10; c++) acc[c] += w * sW[k * 10 + c];
    }
    float* op = out + (size_t)node * 10;
#pragma unroll
    for (int c = 0; c < 10; c++) op[c] = acc[c];
}

extern "C" void kernel_launch(void* const* d_in, const int* in_sizes, int n_in,
                              void* d_out, int out_size, void* d_ws, size_t ws_size,
                              hipStream_t stream) {
    const float* features = (const float*)d_in[0];
    const int* edges = (const int*)d_in[1];
    int n_nodes = in_sizes[0] / FDIM;          // 50000
    int n_edges = in_sizes[1] / 2;             // 800000
    const int* src = edges;
    const int* dst = edges + n_edges;

    // workspace layout: h | xA | xB  (each n_nodes*64 floats)
    size_t buf_elems = (size_t)n_nodes * FDIM;
    float* h  = (float*)d_ws;
    float* xA = h + buf_elems;
    float* xB = xA + buf_elems;

    const int n4 = (int)(buf_elems / 4);
    dim3 bs(256);
    dim3 gs_init((n4 + 255) / 256);
    dim3 gs_scatter((n_edges * 16 + 255) / 256);
    dim3 gs_node((n_nodes + 255) / 256);

    const float* x_cur = features;
    float* outs[3] = {xA, xB, xA};
    for (int conv = 0; conv < 3; conv++) {
        const float* W1 = (const float*)d_in[2 + 4 * conv];
        const float* b1 = (const float*)d_in[3 + 4 * conv];
        const float* W2 = (const float*)d_in[4 + 4 * conv];
        const float* b2 = (const float*)d_in[5 + 4 * conv];

        init_h<<<gs_init, bs, 0, stream>>>(x_cur, h, n4);
        scatter_edges<<<gs_scatter, bs, 0, stream>>>(x_cur, src, dst, h, n_edges);
        mlp_relu<<<gs_node, bs, 0, stream>>>(h, W1, b1, W2, b2, outs[conv], n_nodes);
        x_cur = outs[conv];
    }

    const float* W_lin = (const float*)d_in[14];
    const float* b_lin = (const float*)d_in[15];
    final_linear<<<gs_node, bs, 0, stream>>>(x_cur, W_lin, b_lin, (float*)d_out, n_nodes);
}

// Round 2
// 518.087 us; speedup vs baseline: 4.3484x; 4.3484x over previous
//
#include <hip/hip_runtime.h>
#include <hip/hip_bf16.h>

#define FDIM 64
#define SCAN_THREADS 1024

// histogram of destination degrees
__global__ void hist_dst(const int* __restrict__ dst, int* __restrict__ counts, int n_edges) {
    int e = blockIdx.x * blockDim.x + threadIdx.x;
    if (e < n_edges) atomicAdd(&counts[dst[e]], 1);
}

// single-block exclusive scan over counts -> row_ptr (n+1), cursor copy
__global__ __launch_bounds__(SCAN_THREADS) void build_rowptr(const int* __restrict__ counts,
                                                             int* __restrict__ row_ptr,
                                                             int* __restrict__ cursor,
                                                             int n_nodes) {
    __shared__ int partial[SCAN_THREADS];
    int tid = threadIdx.x;
    int chunk = (n_nodes + SCAN_THREADS - 1) / SCAN_THREADS;
    int beg = tid * chunk;
    int end = min(beg + chunk, n_nodes);
    int s = 0;
    for (int i = beg; i < end; i++) s += counts[i];
    partial[tid] = s;
    __syncthreads();
    // Hillis-Steele inclusive scan
    for (int off = 1; off < SCAN_THREADS; off <<= 1) {
        int v = 0;
        if (tid >= off) v = partial[tid - off];
        __syncthreads();
        if (tid >= off) partial[tid] += v;
        __syncthreads();
    }
    int base = (tid == 0) ? 0 : partial[tid - 1];
    for (int i = beg; i < end; i++) {
        row_ptr[i] = base;
        cursor[i] = base;
        base += counts[i];
    }
    if (tid == SCAN_THREADS - 1) row_ptr[n_nodes] = partial[SCAN_THREADS - 1];
}

// counting-sort fill: src ids grouped by dst
__global__ void fill_csr(const int* __restrict__ src, const int* __restrict__ dst,
                         int* __restrict__ cursor, int* __restrict__ src_sorted, int n_edges) {
    int e = blockIdx.x * blockDim.x + threadIdx.x;
    if (e < n_edges) {
        int pos = atomicAdd(&cursor[dst[e]], 1);
        src_sorted[pos] = src[e];
    }
}

// gather: h[n] = x[n] + sum_{e in row} x[src_sorted[e]] ; 16 threads/node, float4 each
__global__ __launch_bounds__(256) void gather_nodes(const float* __restrict__ x,
                                                    const int* __restrict__ row_ptr,
                                                    const int* __restrict__ src_sorted,
                                                    float* __restrict__ h, int n_nodes) {
    int t = blockIdx.x * blockDim.x + threadIdx.x;
    int node = t >> 4;
    if (node >= n_nodes) return;
    int c = (t & 15) * 4;
    int beg = row_ptr[node];
    int end = row_ptr[node + 1];
    float4 acc = *(const float4*)(x + (size_t)node * FDIM + c);
    for (int e = beg; e < end; e++) {
        int s = src_sorted[e];
        float4 v = *(const float4*)(x + (size_t)s * FDIM + c);
        acc.x += v.x; acc.y += v.y; acc.z += v.z; acc.w += v.w;
    }
    *(float4*)(h + (size_t)node * FDIM + c) = acc;
}

// y = relu( relu(h@W1+b1) @ W2 + b2 )
__global__ __launch_bounds__(256) void mlp_relu(const float* __restrict__ x,
                                                const float* __restrict__ W1,
                                                const float* __restrict__ b1,
                                                const float* __restrict__ W2,
                                                const float* __restrict__ b2,
                                                float* __restrict__ y, int n_nodes) {
    __shared__ float sW1[FDIM * FDIM];
    __shared__ float sW2[FDIM * FDIM];
    __shared__ float sb1[FDIM];
    __shared__ float sb2[FDIM];
    for (int i = threadIdx.x; i < FDIM * FDIM; i += 256) {
        sW1[i] = W1[i];
        sW2[i] = W2[i];
    }
    if (threadIdx.x < FDIM) {
        sb1[threadIdx.x] = b1[threadIdx.x];
        sb2[threadIdx.x] = b2[threadIdx.x];
    }
    __syncthreads();
    int node = blockIdx.x * 256 + threadIdx.x;
    if (node >= n_nodes) return;

    float h[FDIM];
    const float4* xp = (const float4*)(x + (size_t)node * FDIM);
#pragma unroll
    for (int k = 0; k < FDIM / 4; k++) {
        float4 v = xp[k];
        h[4 * k + 0] = v.x; h[4 * k + 1] = v.y;
        h[4 * k + 2] = v.z; h[4 * k + 3] = v.w;
    }
    float g[FDIM];
    for (int j = 0; j < FDIM; j += 4) {
        float a0 = sb1[j + 0], a1 = sb1[j + 1], a2 = sb1[j + 2], a3 = sb1[j + 3];
#pragma unroll
        for (int k = 0; k < FDIM; k++) {
            float w = h[k];
            a0 += w * sW1[k * FDIM + j + 0];
            a1 += w * sW1[k * FDIM + j + 1];
            a2 += w * sW1[k * FDIM + j + 2];
            a3 += w * sW1[k * FDIM + j + 3];
        }
        g[j + 0] = fmaxf(a0, 0.f); g[j + 1] = fmaxf(a1, 0.f);
        g[j + 2] = fmaxf(a2, 0.f); g[j + 3] = fmaxf(a3, 0.f);
    }
    float4* yp = (float4*)(y + (size_t)node * FDIM);
    for (int j = 0; j < FDIM; j += 4) {
        float a0 = sb2[j + 0], a1 = sb2[j + 1], a2 = sb2[j + 2], a3 = sb2[j + 3];
#pragma unroll
        for (int k = 0; k < FDIM; k++) {
            float w = g[k];
            a0 += w * sW2[k * FDIM + j + 0];
            a1 += w * sW2[k * FDIM + j + 1];
            a2 += w * sW2[k * FDIM + j + 2];
            a3 += w * sW2[k * FDIM + j + 3];
        }
        float4 o;
        o.x = fmaxf(a0, 0.f); o.y = fmaxf(a1, 0.f);
        o.z = fmaxf(a2, 0.f); o.w = fmaxf(a3, 0.f);
        yp[j / 4] = o;
    }
}

// out = x @ W_lin + b_lin ; W_lin is (64,10) row-major
__global__ __launch_bounds__(256) void final_linear(const float* __restrict__ x,
                                                    const float* __restrict__ W,
                                                    const float* __restrict__ b,
                                                    float* __restrict__ out, int n_nodes) {
    __shared__ float sW[FDIM * 10];
    __shared__ float sb[10];
    for (int i = threadIdx.x; i < FDIM * 10; i += 256) sW[i] = W[i];
    if (threadIdx.x < 10) sb[threadIdx.x] = b[threadIdx.x];
    __syncthreads();
    int node = blockIdx.x * 256 + threadIdx.x;
    if (node >= n_nodes) return;

    float h[FDIM];
    const float4* xp = (const float4*)(x + (size_t)node * FDIM);
#pragma unroll
    for (int k = 0; k < FDIM / 4; k++) {
        float4 v = xp[k];
        h[4 * k + 0] = v.x; h[4 * k + 1] = v.y;
        h[4 * k + 2] = v.z; h[4 * k + 3] = v.w;
    }
    float acc[10];
#pragma unroll
    for (int c = 0; c < 10; c++) acc[c] = sb[c];
    for (int k = 0; k < FDIM; k++) {
        float w = h[k];
#pragma unroll
        for (int c = 0; c < 10; c++) acc[c] += w * sW[k * 10 + c];
    }
    float* op = out + (size_t)node * 10;
#pragma unroll
    for (int c = 0; c < 10; c++) op[c] = acc[c];
}

extern "C" void kernel_launch(void* const* d_in, const int* in_sizes, int n_in,
                              void* d_out, int out_size, void* d_ws, size_t ws_size,
                              hipStream_t stream) {
    const float* features = (const float*)d_in[0];
    const int* edges = (const int*)d_in[1];
    int n_nodes = in_sizes[0] / FDIM;          // 50000
    int n_edges = in_sizes[1] / 2;             // 800000
    const int* src = edges;
    const int* dst = edges + n_edges;

    // workspace layout (ints first, then float buffers, 16B-aligned)
    int* counts = (int*)d_ws;                        // n_nodes
    int* cursor = counts + n_nodes;                  // n_nodes
    int* row_ptr = cursor + n_nodes;                 // n_nodes + 1
    int* src_sorted = row_ptr + (n_nodes + 1);       // n_edges
    size_t int_elems = (size_t)(3 * n_nodes + 1 + n_edges);
    int_elems = (int_elems + 3) & ~(size_t)3;        // 16B align
    float* h  = (float*)d_ws + int_elems;
    size_t buf_elems = (size_t)n_nodes * FDIM;
    float* xA = h + buf_elems;
    float* xB = xA + buf_elems;

    dim3 bs(256);
    dim3 gs_edge((n_edges + 255) / 256);
    dim3 gs_gather((n_nodes * 16 + 255) / 256);
    dim3 gs_node((n_nodes + 255) / 256);

    // --- build CSR (dst-grouped) ---
    hipMemsetAsync(counts, 0, (size_t)n_nodes * sizeof(int), stream);
    hist_dst<<<gs_edge, bs, 0, stream>>>(dst, counts, n_edges);
    build_rowptr<<<1, SCAN_THREADS, 0, stream>>>(counts, row_ptr, cursor, n_nodes);
    fill_csr<<<gs_edge, bs, 0, stream>>>(src, dst, cursor, src_sorted, n_edges);

    // --- 3 GIN convs ---
    const float* x_cur = features;
    float* outs[3] = {xA, xB, xA};
    for (int conv = 0; conv < 3; conv++) {
        const float* W1 = (const float*)d_in[2 + 4 * conv];
        const float* b1 = (const float*)d_in[3 + 4 * conv];
        const float* W2 = (const float*)d_in[4 + 4 * conv];
        const float* b2 = (const float*)d_in[5 + 4 * conv];

        gather_nodes<<<gs_gather, bs, 0, stream>>>(x_cur, row_ptr, src_sorted, h, n_nodes);
        mlp_relu<<<gs_node, bs, 0, stream>>>(h, W1, b1, W2, b2, outs[conv], n_nodes);
        x_cur = outs[conv];
    }

    const float* W_lin = (const float*)d_in[14];
    const float* b_lin = (const float*)d_in[15];
    final_linear<<<gs_node, bs, 0, stream>>>(x_cur, W_lin, b_lin, (float*)d_out, n_nodes);
}

// Round 3
// 369.234 us; speedup vs baseline: 6.1015x; 1.4031x over previous
//
#include <hip/hip_runtime.h>
#include <hip/hip_bf16.h>

#define FDIM 64
#define SCAN_BLK 256
#define HPAD 68  // 64 + 4 pad: shifts banks by 4 per node row

// histogram of destination degrees
__global__ void hist_dst(const int* __restrict__ dst, int* __restrict__ counts, int n_edges) {
    int e = blockIdx.x * blockDim.x + threadIdx.x;
    if (e < n_edges) atomicAdd(&counts[dst[e]], 1);
}

// phase 1: per-block sum of counts
__global__ __launch_bounds__(SCAN_BLK) void scan_reduce(const int* __restrict__ counts,
                                                        int* __restrict__ bsum, int n) {
    __shared__ int s[SCAN_BLK];
    int i = blockIdx.x * SCAN_BLK + threadIdx.x;
    s[threadIdx.x] = (i < n) ? counts[i] : 0;
    __syncthreads();
    for (int off = SCAN_BLK / 2; off > 0; off >>= 1) {
        if (threadIdx.x < off) s[threadIdx.x] += s[threadIdx.x + off];
        __syncthreads();
    }
    if (threadIdx.x == 0) bsum[blockIdx.x] = s[0];
}

// phase 2: single-block exclusive scan of block sums (nblocks <= SCAN_BLK)
__global__ __launch_bounds__(SCAN_BLK) void scan_sums(const int* __restrict__ bsum,
                                                      int* __restrict__ bofs,
                                                      int* __restrict__ row_ptr,
                                                      int nblocks, int n_nodes, int n_edges) {
    __shared__ int s[SCAN_BLK];
    int tid = threadIdx.x;
    s[tid] = (tid < nblocks) ? bsum[tid] : 0;
    __syncthreads();
    for (int off = 1; off < SCAN_BLK; off <<= 1) {
        int v = (tid >= off) ? s[tid - off] : 0;
        __syncthreads();
        s[tid] += v;
        __syncthreads();
    }
    if (tid < nblocks) bofs[tid] = (tid == 0) ? 0 : s[tid - 1];
    if (tid == 0) row_ptr[n_nodes] = n_edges;
}

// phase 3: per-block exclusive scan + offset -> row_ptr, cursor
__global__ __launch_bounds__(SCAN_BLK) void scan_write(const int* __restrict__ counts,
                                                       const int* __restrict__ bofs,
                                                       int* __restrict__ row_ptr,
                                                       int* __restrict__ cursor, int n) {
    __shared__ int s[SCAN_BLK];
    int tid = threadIdx.x;
    int i = blockIdx.x * SCAN_BLK + tid;
    int v = (i < n) ? counts[i] : 0;
    s[tid] = v;
    __syncthreads();
    for (int off = 1; off < SCAN_BLK; off <<= 1) {
        int u = (tid >= off) ? s[tid - off] : 0;
        __syncthreads();
        s[tid] += u;
        __syncthreads();
    }
    if (i < n) {
        int ex = bofs[blockIdx.x] + s[tid] - v;  // exclusive
        row_ptr[i] = ex;
        cursor[i] = ex;
    }
}

// counting-sort fill: src ids grouped by dst
__global__ void fill_csr(const int* __restrict__ src, const int* __restrict__ dst,
                         int* __restrict__ cursor, int* __restrict__ src_sorted, int n_edges) {
    int e = blockIdx.x * blockDim.x + threadIdx.x;
    if (e < n_edges) {
        int pos = atomicAdd(&cursor[dst[e]], 1);
        src_sorted[pos] = src[e];
    }
}

// gather: h[n] = x[n] + sum_{e in row} x[src_sorted[e]] ; 16 threads/node, float4 each
__global__ __launch_bounds__(256) void gather_nodes(const float* __restrict__ x,
                                                    const int* __restrict__ row_ptr,
                                                    const int* __restrict__ src_sorted,
                                                    float* __restrict__ h, int n_nodes) {
    int t = blockIdx.x * blockDim.x + threadIdx.x;
    int node = t >> 4;
    if (node >= n_nodes) return;
    int c = (t & 15) * 4;
    int beg = row_ptr[node];
    int end = row_ptr[node + 1];
    float4 acc = *(const float4*)(x + (size_t)node * FDIM + c);
    int e = beg;
    for (; e + 1 < end; e += 2) {
        int s0 = src_sorted[e];
        int s1 = src_sorted[e + 1];
        float4 v0 = *(const float4*)(x + (size_t)s0 * FDIM + c);
        float4 v1 = *(const float4*)(x + (size_t)s1 * FDIM + c);
        acc.x += v0.x + v1.x; acc.y += v0.y + v1.y;
        acc.z += v0.z + v1.z; acc.w += v0.w + v1.w;
    }
    if (e < end) {
        int s0 = src_sorted[e];
        float4 v0 = *(const float4*)(x + (size_t)s0 * FDIM + c);
        acc.x += v0.x; acc.y += v0.y; acc.z += v0.z; acc.w += v0.w;
    }
    *(float4*)(h + (size_t)node * FDIM + c) = acc;
}

// MLP, 16 threads per node: thread (node_local = tid>>4, jq = tid&15) computes
// 4 output features. h/g tiles in padded LDS; W1/W2 staged in LDS.
__global__ __launch_bounds__(256) void mlp_relu2(const float* __restrict__ x,
                                                 const float* __restrict__ W1,
                                                 const float* __restrict__ b1,
                                                 const float* __restrict__ W2,
                                                 const float* __restrict__ b2,
                                                 float* __restrict__ y, int n_nodes) {
    __shared__ float sW1[FDIM * FDIM];
    __shared__ float sW2[FDIM * FDIM];
    __shared__ float sb1[FDIM];
    __shared__ float sb2[FDIM];
    __shared__ float sh[16 * HPAD];
    __shared__ float sg[16 * HPAD];
    int tid = threadIdx.x;
    for (int i = tid; i < FDIM * FDIM; i += 256) {
        sW1[i] = W1[i];
        sW2[i] = W2[i];
    }
    if (tid < FDIM) { sb1[tid] = b1[tid]; sb2[tid] = b2[tid]; }

    int base = blockIdx.x * 16;
    {   // stage h tile: 16 nodes x 64 floats, one float4 per thread, coalesced
        int n = tid >> 4;
        int c4 = (tid & 15) * 4;
        float4 v = *(const float4*)(x + (size_t)(base + n) * FDIM + c4);
        *(float4*)(&sh[n * HPAD + c4]) = v;
    }
    __syncthreads();

    int nl = tid >> 4;
    int jq = (tid & 15) * 4;

    // layer 1: g = relu(h @ W1 + b1)
    float a0 = sb1[jq], a1 = sb1[jq + 1], a2 = sb1[jq + 2], a3 = sb1[jq + 3];
#pragma unroll
    for (int k0 = 0; k0 < FDIM; k0 += 4) {
        float4 hv = *(float4*)(&sh[nl * HPAD + k0]);
        float4 w0 = *(float4*)(&sW1[(k0 + 0) * FDIM + jq]);
        float4 w1 = *(float4*)(&sW1[(k0 + 1) * FDIM + jq]);
        float4 w2 = *(float4*)(&sW1[(k0 + 2) * FDIM + jq]);
        float4 w3 = *(float4*)(&sW1[(k0 + 3) * FDIM + jq]);
        a0 += hv.x * w0.x + hv.y * w1.x + hv.z * w2.x + hv.w * w3.x;
        a1 += hv.x * w0.y + hv.y * w1.y + hv.z * w2.y + hv.w * w3.y;
        a2 += hv.x * w0.z + hv.y * w1.z + hv.z * w2.z + hv.w * w3.z;
        a3 += hv.x * w0.w + hv.y * w1.w + hv.z * w2.w + hv.w * w3.w;
    }
    float4 gq;
    gq.x = fmaxf(a0, 0.f); gq.y = fmaxf(a1, 0.f);
    gq.z = fmaxf(a2, 0.f); gq.w = fmaxf(a3, 0.f);
    *(float4*)(&sg[nl * HPAD + jq]) = gq;
    __syncthreads();

    // layer 2: y = relu(g @ W2 + b2)
    float c0 = sb2[jq], c1 = sb2[jq + 1], c2 = sb2[jq + 2], c3 = sb2[jq + 3];
#pragma unroll
    for (int k0 = 0; k0 < FDIM; k0 += 4) {
        float4 gv = *(float4*)(&sg[nl * HPAD + k0]);
        float4 w0 = *(float4*)(&sW2[(k0 + 0) * FDIM + jq]);
        float4 w1 = *(float4*)(&sW2[(k0 + 1) * FDIM + jq]);
        float4 w2 = *(float4*)(&sW2[(k0 + 2) * FDIM + jq]);
        float4 w3 = *(float4*)(&sW2[(k0 + 3) * FDIM + jq]);
        c0 += gv.x * w0.x + gv.y * w1.x + gv.z * w2.x + gv.w * w3.x;
        c1 += gv.x * w0.y + gv.y * w1.y + gv.z * w2.y + gv.w * w3.y;
        c2 += gv.x * w0.z + gv.y * w1.z + gv.z * w2.z + gv.w * w3.z;
        c3 += gv.x * w0.w + gv.y * w1.w + gv.z * w2.w + gv.w * w3.w;
    }
    float4 o;
    o.x = fmaxf(c0, 0.f); o.y = fmaxf(c1, 0.f);
    o.z = fmaxf(c2, 0.f); o.w = fmaxf(c3, 0.f);
    *(float4*)(y + (size_t)(base + nl) * FDIM + jq) = o;
}

// out = x @ W_lin + b_lin ; W_lin is (64,10) row-major
__global__ __launch_bounds__(256) void final_linear(const float* __restrict__ x,
                                                    const float* __restrict__ W,
                                                    const float* __restrict__ b,
                                                    float* __restrict__ out, int n_nodes) {
    __shared__ float sW[FDIM * 10];
    __shared__ float sb[10];
    for (int i = threadIdx.x; i < FDIM * 10; i += 256) sW[i] = W[i];
    if (threadIdx.x < 10) sb[threadIdx.x] = b[threadIdx.x];
    __syncthreads();
    int node = blockIdx.x * 256 + threadIdx.x;
    if (node >= n_nodes) return;

    float h[FDIM];
    const float4* xp = (const float4*)(x + (size_t)node * FDIM);
#pragma unroll
    for (int k = 0; k < FDIM / 4; k++) {
        float4 v = xp[k];
        h[4 * k + 0] = v.x; h[4 * k + 1] = v.y;
        h[4 * k + 2] = v.z; h[4 * k + 3] = v.w;
    }
    float acc[10];
#pragma unroll
    for (int c = 0; c < 10; c++) acc[c] = sb[c];
    for (int k = 0; k < FDIM; k++) {
        float w = h[k];
#pragma unroll
        for (int c = 0; c < 10; c++) acc[c] += w * sW[k * 10 + c];
    }
    float* op = out + (size_t)node * 10;
#pragma unroll
    for (int c = 0; c < 10; c++) op[c] = acc[c];
}

extern "C" void kernel_launch(void* const* d_in, const int* in_sizes, int n_in,
                              void* d_out, int out_size, void* d_ws, size_t ws_size,
                              hipStream_t stream) {
    const float* features = (const float*)d_in[0];
    const int* edges = (const int*)d_in[1];
    int n_nodes = in_sizes[0] / FDIM;          // 50000
    int n_edges = in_sizes[1] / 2;             // 800000
    const int* src = edges;
    const int* dst = edges + n_edges;

    int nscan = (n_nodes + SCAN_BLK - 1) / SCAN_BLK;   // 196

    // workspace layout (ints first, then float buffers, 16B-aligned)
    int* counts = (int*)d_ws;                        // n_nodes
    int* cursor = counts + n_nodes;                  // n_nodes
    int* row_ptr = cursor + n_nodes;                 // n_nodes + 1
    int* src_sorted = row_ptr + (n_nodes + 1);       // n_edges
    int* bsum = src_sorted + n_edges;                // nscan
    int* bofs = bsum + nscan;                        // nscan
    size_t int_elems = (size_t)(3 * n_nodes + 1 + n_edges + 2 * nscan);
    int_elems = (int_elems + 3) & ~(size_t)3;        // 16B align
    float* h  = (float*)d_ws + int_elems;
    size_t buf_elems = (size_t)n_nodes * FDIM;
    float* xA = h + buf_elems;
    float* xB = xA + buf_elems;

    dim3 bs(256);
    dim3 gs_edge((n_edges + 255) / 256);
    dim3 gs_gather((n_nodes * 16 + 255) / 256);
    dim3 gs_node((n_nodes + 255) / 256);
    dim3 gs_mlp(n_nodes / 16);  // 50000/16 = 3125, exact
    dim3 gs_scan(nscan);

    // --- build CSR (dst-grouped) ---
    hipMemsetAsync(counts, 0, (size_t)n_nodes * sizeof(int), stream);
    hist_dst<<<gs_edge, bs, 0, stream>>>(dst, counts, n_edges);
    scan_reduce<<<gs_scan, SCAN_BLK, 0, stream>>>(counts, bsum, n_nodes);
    scan_sums<<<1, SCAN_BLK, 0, stream>>>(bsum, bofs, row_ptr, nscan, n_nodes, n_edges);
    scan_write<<<gs_scan, SCAN_BLK, 0, stream>>>(counts, bofs, row_ptr, cursor, n_nodes);
    fill_csr<<<gs_edge, bs, 0, stream>>>(src, dst, cursor, src_sorted, n_edges);

    // --- 3 GIN convs ---
    const float* x_cur = features;
    float* outs[3] = {xA, xB, xA};
    for (int conv = 0; conv < 3; conv++) {
        const float* W1 = (const float*)d_in[2 + 4 * conv];
        const float* b1 = (const float*)d_in[3 + 4 * conv];
        const float* W2 = (const float*)d_in[4 + 4 * conv];
        const float* b2 = (const float*)d_in[5 + 4 * conv];

        gather_nodes<<<gs_gather, bs, 0, stream>>>(x_cur, row_ptr, src_sorted, h, n_nodes);
        mlp_relu2<<<gs_mlp, bs, 0, stream>>>(h, W1, b1, W2, b2, outs[conv], n_nodes);
        x_cur = outs[conv];
    }

    const float* W_lin = (const float*)d_in[14];
    const float* b_lin = (const float*)d_in[15];
    final_linear<<<gs_node, bs, 0, stream>>>(x_cur, W_lin, b_lin, (float*)d_out, n_nodes);
}